// Round 6
// baseline (1942.540 us; speedup 1.0000x reference)
//
#include <hip/hip_runtime.h>
#include <stdint.h>

#define DEVINL __device__ __forceinline__

typedef __attribute__((ext_vector_type(8))) __bf16 bf16x8;
typedef __attribute__((ext_vector_type(8))) unsigned short ushort8;
typedef __attribute__((ext_vector_type(4))) float floatx4;

constexpr int E_ = 256;
constexpr int TAGS = 22, ST_START = 20, ST_STOP = 21;
constexpr int B_ = 128, S_ = 256, BS_ = B_ * S_;
constexpr int NG = 1024;  // 4*H

DEVINL uint16_t f2bf(float f) {  // RNE f32->bf16 (no NaN inputs expected)
  uint32_t u = __builtin_bit_cast(uint32_t, f);
  return (uint16_t)((u + 0x7fffu + ((u >> 16) & 1u)) >> 16);
}
DEVINL float bf2f(uint16_t h) {
  uint32_t u = ((uint32_t)h) << 16;
  return __builtin_bit_cast(float, u);
}
DEVINL uint4 pack8(float4 a, float4 b) {
  ushort8 h;
  h[0] = f2bf(a.x); h[1] = f2bf(a.y); h[2] = f2bf(a.z); h[3] = f2bf(a.w);
  h[4] = f2bf(b.x); h[5] = f2bf(b.y); h[6] = f2bf(b.z); h[7] = f2bf(b.w);
  return __builtin_bit_cast(uint4, h);
}
DEVINL floatx4 mfma16(uint4 a, uint4 b, floatx4 c) {
  return __builtin_amdgcn_mfma_f32_16x16x32_bf16(
      __builtin_bit_cast(bf16x8, a), __builtin_bit_cast(bf16x8, b), c, 0, 0, 0);
}
DEVINL float sigf(float x) { return 1.f / (1.f + __expf(-x)); }
DEVINL float tanh_(float x) { return 1.f - 2.f / (__expf(2.f * x) + 1.f); }

// ---------------- init: zero output (ws is poisoned 0xAA) ----------
__global__ void k_init(float* out, int out_n) {
  int t = threadIdx.x;
  if (t < out_n) out[t] = 0.f;
}

// ---------------- f32 -> bf16 weight conversion ----------------
__global__ void k_f2bf(const float* __restrict__ src, uint16_t* __restrict__ dst, int n) {
  int i = blockIdx.x * blockDim.x + threadIdx.x;
  int stride = gridDim.x * blockDim.x;
  for (; i < n; i += stride) dst[i] = f2bf(src[i]);
}

// ---------------- xg GEMM: out[m, ng] = A[m,:] . wb[ng,:]  (ng = dir*1024+n) ----
template <bool EMBED, int K>
__global__ __launch_bounds__(256) void k_gemm(
    const float* __restrict__ emb, const int* __restrict__ word,
    const uint16_t* __restrict__ xa, const uint16_t* __restrict__ wb,
    uint16_t* __restrict__ xg) {
  __shared__ uint4 As[8 * 128];  // [k8][m][8] bf16, 16KB
  __shared__ uint4 Bs[8 * 128];  // [k8][n][8] bf16, 16KB
  const int tid = threadIdx.x;
  const int bx = blockIdx.x;
  const int m0 = (bx & 255) << 7;
  const int n0 = (bx >> 8) << 7;
  const int lane = tid & 63, w = tid >> 6;
  const int ln = lane & 15, q = lane >> 4;
  const int wm = w & 1, wn = w >> 1;

  floatx4 acc[4][4];
#pragma unroll
  for (int a = 0; a < 4; a++)
#pragma unroll
    for (int b = 0; b < 4; b++) acc[a][b] = (floatx4){0.f, 0.f, 0.f, 0.f};

  for (int k0 = 0; k0 < K; k0 += 64) {
#pragma unroll
    for (int it = 0; it < 4; it++) {
      int c = tid + it * 256;  // 0..1023
      int k8 = c & 7, r = c >> 3;
      if (EMBED) {
        int row = word[m0 + r];
        const float* sp = emb + (size_t)row * E_ + k0 + k8 * 8;
        float4 f0 = *(const float4*)sp;
        float4 f1 = *(const float4*)(sp + 4);
        As[k8 * 128 + r] = pack8(f0, f1);
      } else {
        As[k8 * 128 + r] = *(const uint4*)(xa + (size_t)(m0 + r) * K + k0 + k8 * 8);
      }
      Bs[k8 * 128 + r] = *(const uint4*)(wb + (size_t)(n0 + r) * K + k0 + k8 * 8);
    }
    __syncthreads();
#pragma unroll
    for (int kk = 0; kk < 2; kk++) {
      const int k4b = kk * 4 + q;
      uint4 af[4], bf[4];
#pragma unroll
      for (int mt = 0; mt < 4; mt++) af[mt] = As[k4b * 128 + wm * 64 + mt * 16 + ln];
#pragma unroll
      for (int nt = 0; nt < 4; nt++) bf[nt] = Bs[k4b * 128 + wn * 64 + nt * 16 + ln];
#pragma unroll
      for (int mt = 0; mt < 4; mt++)
#pragma unroll
        for (int nt = 0; nt < 4; nt++) acc[mt][nt] = mfma16(af[mt], bf[nt], acc[mt][nt]);
    }
    __syncthreads();
  }
#pragma unroll
  for (int mt = 0; mt < 4; mt++) {
    int Rb = m0 + wm * 64 + mt * 16 + q * 4;
#pragma unroll
    for (int nt = 0; nt < 4; nt++) {
      int C = n0 + wn * 64 + nt * 16 + ln;
      size_t base = (size_t)(C >> 10) * ((size_t)BS_ * NG) + (C & 1023);
#pragma unroll
      for (int r = 0; r < 4; r++) xg[base + (size_t)(Rb + r) * NG] = f2bf(acc[mt][nt][r]);
    }
  }
}

// ---------------- BiLSTM recurrence (one layer, both dirs) ----------------
// 64 WGs x 256 thr, 1 WG/CU. group = (dir, batch-tile of 32) -> 8 groups, 8
// members each owning 32 h-cols (128 gate rows). w_hh B-frags live in VGPRs
// (loaded once via LDS). Wave (mh,jh) computes ALL 4 gates for its 16m x 16j
// -> state update entirely in MFMA output registers; ONE barrier per step.
// Cross-WG h exchange: epoch-stamped 8B entries {epoch|hpack} at the coherent
// point via relaxed agent atomics (protocol identical to R3-R5, deadlock-free:
// no wave can lead by 2 steps since each gather needs all members' publishes).
__global__ __launch_bounds__(256, 1) void k_rec(
    const uint16_t* __restrict__ xg, const float* __restrict__ w_hh,
    const float* __restrict__ b_ih, const float* __restrict__ b_hh,
    uint16_t* __restrict__ xout, uint64_t* __restrict__ hbuf, int ebase) {
  __shared__ uint4 Wl[32 * 128];        // 64KB weight staging [k4b][nloc(128)]
  __shared__ uint32_t hA32[2 * 4096];   // 32KB double-buffered A-frag h
  __shared__ uint32_t xstage[8 * 512];  // 16KB [slot(8)][jpl(16)][m(32)]

  const int tid = threadIdx.x;
  const int wg = blockIdx.x;
  const int group = wg & 7, member = wg >> 3;    // 8 groups x 8 members
  const int dir = group & 1, tile = group >> 1;  // 4 tiles of 32 rows
  const int j0m = member * 32;
  const int lane = tid & 63, w = tid >> 6, ln = lane & 15, q = lane >> 4;
  const int mh = w >> 1, jh = w & 1;  // wave: m-half, j-half

  // stage member's w_hh slice (128 gate rows = 4 gates x 32 j) as B-frags.
  // nloc = (jj>>4)*64 + g*16 + (jj&15)
  for (int p = tid; p < 4096; p += 256) {
    int nloc = p & 127, k4 = p >> 7;
    int g = (nloc >> 4) & 3, jj = (nloc >> 6) * 16 + (nloc & 15);
    int row = dir * 1024 + g * 256 + j0m + jj;
    const float* sp = w_hh + (size_t)row * 256 + k4 * 8;
    Wl[k4 * 128 + nloc] = pack8(*(const float4*)sp, *(const float4*)(sp + 4));
  }
  const int j = j0m + jh * 16 + ln;  // hidden col 0..255
  float brg[4];
#pragma unroll
  for (int g = 0; g < 4; g++) brg[g] = b_ih[dir * 1024 + g * 256 + j] +
                                       b_hh[dir * 1024 + g * 256 + j];
  __syncthreads();

  // hoist B-frags into registers: 32 x uint4 = 128 VGPRs (static all steps)
  uint4 Wb[8][4];
#pragma unroll
  for (int kk = 0; kk < 8; kk++)
#pragma unroll
    for (int g = 0; g < 4; g++)
      Wb[kk][g] = Wl[(kk * 4 + q) * 128 + jh * 64 + g * 16 + ln];

  const uint16_t* xgd = xg + (size_t)dir * BS_ * NG;
  const int mbase = mh * 16 + q * 4;      // group-local m for acc rows r=0..3
  const int mrow0 = tile * 32 + mbase;    // global batch row base
  const bool even = (ln & 1) == 0;
  const int jp = j >> 1;                  // j-pair index (valid on even lanes)
  const int jpl = jh * 8 + (ln >> 1);     // member-local j-pair 0..15

  float c[4] = {0.f, 0.f, 0.f, 0.f};
  uint16_t xv[16];
  int sg = dir ? 255 : 0;
#pragma unroll
  for (int g = 0; g < 4; g++)
#pragma unroll
    for (int r = 0; r < 4; r++)
      xv[g * 4 + r] = xgd[(size_t)((mrow0 + r) * 256 + sg) * NG + g * 256 + j];

  for (int t = 0; t < 256; t++) {
    sg = dir ? (255 - t) : t;
    floatx4 acc[4];
#pragma unroll
    for (int g = 0; g < 4; g++) acc[g] = (floatx4){0.f, 0.f, 0.f, 0.f};
    if (t > 0) {
      // gather h(t-1): batched parallel poll of 16 epoch-stamped entries/thread
      const uint64_t* hsrc = hbuf + (size_t)((((t - 1) & 1) * 8) + group) * 4096;
      const uint32_t want = (uint32_t)(ebase + t);
      uint64_t v[16];
      while (true) {
#pragma unroll
        for (int i = 0; i < 16; i++)
          v[i] = __hip_atomic_load(&hsrc[tid + 256 * i], __ATOMIC_RELAXED,
                                   __HIP_MEMORY_SCOPE_AGENT);
        bool fresh = true;
#pragma unroll
        for (int i = 0; i < 16; i++) fresh &= ((uint32_t)(v[i] >> 32) == want);
        if (fresh) break;
        __builtin_amdgcn_s_sleep(2);
      }
      uint32_t* hAw = hA32 + (t & 1) * 4096;
#pragma unroll
      for (int i = 0; i < 16; i++) hAw[tid + 256 * i] = (uint32_t)v[i];
      __syncthreads();
      const uint4* hAv = (const uint4*)(hA32 + (t & 1) * 4096);
#pragma unroll
      for (int kk = 0; kk < 8; kk++) {
        uint4 a = hAv[(kk * 4 + q) * 32 + mh * 16 + ln];
#pragma unroll
        for (int g = 0; g < 4; g++) acc[g] = mfma16(a, Wb[kk][g], acc[g]);
      }
    }
    // gates + state entirely in registers (order i,f,g,o)
    float hr[4];
#pragma unroll
    for (int r = 0; r < 4; r++) {
      float pi = acc[0][r] + bf2f(xv[0 + r]) + brg[0];
      float pf = acc[1][r] + bf2f(xv[4 + r]) + brg[1];
      float pg = acc[2][r] + bf2f(xv[8 + r]) + brg[2];
      float po = acc[3][r] + bf2f(xv[12 + r]) + brg[3];
      c[r] = sigf(pf) * c[r] + sigf(pi) * tanh_(pg);
      hr[r] = sigf(po) * tanh_(c[r]);
    }
    // publish ASAP (critical path): pack j-pairs via shfl, 8B entries
    uint32_t hp[4];
#pragma unroll
    for (int r = 0; r < 4; r++) {
      float hn = __shfl_xor(hr[r], 1);
      hp[r] = (uint32_t)f2bf(hr[r]) | ((uint32_t)f2bf(hn) << 16);
    }
    if (even && t < 255) {
      uint64_t* hdst = hbuf + (size_t)(((t & 1) * 8) + group) * 4096;
      const uint64_t ep = ((uint64_t)(uint32_t)(ebase + t + 1)) << 32;
#pragma unroll
      for (int r = 0; r < 4; r++) {
        int e = (jp >> 2) * 128 + (mbase + r) * 4 + (jp & 3);
        __hip_atomic_store(&hdst[e], ep | (uint64_t)hp[r], __ATOMIC_RELAXED,
                           __HIP_MEMORY_SCOPE_AGENT);
      }
    }
    // xv prefetch for t+1 (off critical path)
    {
      int tn = (t < 255) ? t + 1 : 255;
      int sgn = dir ? (255 - tn) : tn;
#pragma unroll
      for (int g = 0; g < 4; g++)
#pragma unroll
        for (int r = 0; r < 4; r++)
          xv[g * 4 + r] = xgd[(size_t)((mrow0 + r) * 256 + sgn) * NG + g * 256 + j];
    }
    // stage h for xout
    if (even) {
#pragma unroll
      for (int r = 0; r < 4; r++)
        xstage[(t & 7) * 512 + jpl * 32 + mbase + r] = hp[r];
    }
    if ((t & 7) == 7) {
      __syncthreads();  // xstage writes visible; safe vs next step (its barrier)
      int m = tid & 31, u = tid >> 5;
      int tt = t - 7 + u;
      int ssg = dir ? (255 - tt) : tt;
      uint32_t d[16];
#pragma unroll
      for (int k = 0; k < 16; k++) d[k] = xstage[u * 512 + k * 32 + m];
      uint16_t* dst = xout + ((size_t)(tile * 32 + m) * 256 + ssg) * 512 + dir * 256 + j0m;
      ((uint4*)dst)[0] = (uint4){d[0], d[1], d[2], d[3]};
      ((uint4*)dst)[1] = (uint4){d[4], d[5], d[6], d[7]};
      ((uint4*)dst)[2] = (uint4){d[8], d[9], d[10], d[11]};
      ((uint4*)dst)[3] = (uint4){d[12], d[13], d[14], d[15]};
    }
  }
}

// ---------------- LayerNorm + projection to 22 tags ----------------
__global__ __launch_bounds__(256) void k_lnproj(
    const uint16_t* __restrict__ x2, const float* __restrict__ ln_g,
    const float* __restrict__ ln_b, const float* __restrict__ w_out,
    const float* __restrict__ b_out, float* __restrict__ feats) {
  const int w = threadIdx.x >> 6, lane = threadIdx.x & 63;
  const int row = blockIdx.x * 4 + w;
  ushort8 xu = __builtin_bit_cast(ushort8, *((const uint4*)(x2 + (size_t)row * 512) + lane));
  float f[8];
  float s = 0.f, ss = 0.f;
#pragma unroll
  for (int j = 0; j < 8; j++) {
    f[j] = bf2f(xu[j]);
    s += f[j];
    ss += f[j] * f[j];
  }
#pragma unroll
  for (int o = 1; o < 64; o <<= 1) {
    s += __shfl_xor(s, o, 64);
    ss += __shfl_xor(ss, o, 64);
  }
  float mu = s * (1.f / 512.f);
  float var = ss * (1.f / 512.f) - mu * mu;
  float rs = rsqrtf(var + 1e-5f);
  const float4 g0 = *(const float4*)(ln_g + lane * 8);
  const float4 g1 = *(const float4*)(ln_g + lane * 8 + 4);
  const float4 bb0 = *(const float4*)(ln_b + lane * 8);
  const float4 bb1 = *(const float4*)(ln_b + lane * 8 + 4);
  float gl[8] = {g0.x, g0.y, g0.z, g0.w, g1.x, g1.y, g1.z, g1.w};
  float bl[8] = {bb0.x, bb0.y, bb0.z, bb0.w, bb1.x, bb1.y, bb1.z, bb1.w};
  float xh[8];
#pragma unroll
  for (int j = 0; j < 8; j++) xh[j] = (f[j] - mu) * rs * gl[j] + bl[j];
  float* fr = feats + (size_t)row * TAGS;
  for (int tg = 0; tg < TAGS; tg++) {
    const float4 w0 = *(const float4*)(w_out + tg * 512 + lane * 8);
    const float4 w1 = *(const float4*)(w_out + tg * 512 + lane * 8 + 4);
    float p = xh[0] * w0.x + xh[1] * w0.y + xh[2] * w0.z + xh[3] * w0.w + xh[4] * w1.x +
              xh[5] * w1.y + xh[6] * w1.z + xh[7] * w1.w;
#pragma unroll
    for (int o = 1; o < 64; o <<= 1) p += __shfl_xor(p, o, 64);
    if (lane == 0) fr[tg] = p + b_out[tg];
  }
}

// ---------------- CRF NLL: one wave per batch row ----------------
__global__ __launch_bounds__(64) void k_crf(
    const float* __restrict__ feats, const float* __restrict__ trans,
    const int* __restrict__ mask, const int* __restrict__ tags, float* __restrict__ out) {
  const int b = blockIdx.x, j = threadIdx.x;
  const bool act = j < TAGS;
  float tcol[TAGS];
#pragma unroll
  for (int i = 0; i < TAGS; i++) tcol[i] = act ? trans[i * TAGS + j] : 0.f;
  const float tstop = act ? trans[j * TAGS + ST_STOP] : 0.f;
  const float* fb = feats + (size_t)b * 256 * TAGS;
  const int* mb = mask + b * 256;
  const int* tb = tags + b * 256;
  float alpha = act ? (tcol[ST_START] + fb[j]) : -1e30f;
  for (int t = 1; t < 256; t++) {
    float vv[TAGS];
    float mx = -1e30f;
#pragma unroll
    for (int i = 0; i < TAGS; i++) {
      float v = __shfl(alpha, i, 64) + tcol[i];
      vv[i] = v;
      mx = fmaxf(mx, v);
    }
    float s = 0.f;
#pragma unroll
    for (int i = 0; i < TAGS; i++) s += __expf(vv[i] - mx);
    float nw = mx + __logf(s) + (act ? fb[t * TAGS + j] : 0.f);
    if (act && mb[t] > 0) alpha = nw;
  }
  float z = act ? (alpha + tstop) : -1e30f;
  float mz = z;
#pragma unroll
  for (int o = 1; o < 64; o <<= 1) mz = fmaxf(mz, __shfl_xor(mz, o, 64));
  float se = act ? __expf(z - mz) : 0.f;
#pragma unroll
  for (int o = 1; o < 64; o <<= 1) se += __shfl_xor(se, o, 64);
  float logZ = mz + __logf(se);
  float em = 0.f;
  int cnt = 0;
  for (int tt = j; tt < 256; tt += 64) {
    int m = mb[tt];
    cnt += m;
    if (m > 0) em += fb[tt * TAGS + tb[tt]];
  }
#pragma unroll
  for (int o = 1; o < 64; o <<= 1) {
    em += __shfl_xor(em, o, 64);
    cnt += __shfl_xor(cnt, o, 64);
  }
  float tr = 0.f;
  for (int tt = 1 + j; tt < 256; tt += 64)
    if (mb[tt] > 0) tr += trans[tb[tt - 1] * TAGS + tb[tt]];
#pragma unroll
  for (int o = 1; o < 64; o <<= 1) tr += __shfl_xor(tr, o, 64);
  if (j == 0) {
    tr += trans[ST_START * TAGS + tb[0]];
    int last = cnt - 1;
    tr += trans[tb[last] * TAGS + ST_STOP];
    atomicAdd(out, (logZ - em - tr) * (1.f / 128.f));
  }
}

extern "C" void kernel_launch(void* const* d_in, const int* in_sizes, int n_in, void* d_out,
                              int out_size, void* d_ws, size_t ws_size, hipStream_t stream) {
  (void)in_sizes;
  (void)n_in;
  const float* emb = (const float*)d_in[0];
  const float* w_ih0 = (const float*)d_in[1];
  const float* w_hh0 = (const float*)d_in[2];
  const float* b_ih0 = (const float*)d_in[3];
  const float* b_hh0 = (const float*)d_in[4];
  const float* w_ih1 = (const float*)d_in[5];
  const float* w_hh1 = (const float*)d_in[6];
  const float* b_ih1 = (const float*)d_in[7];
  const float* b_hh1 = (const float*)d_in[8];
  const float* ln_g = (const float*)d_in[9];
  const float* ln_b = (const float*)d_in[10];
  const float* w_out = (const float*)d_in[11];
  const float* b_out = (const float*)d_in[12];
  const float* trans = (const float*)d_in[13];
  const int* word = (const int*)d_in[14];
  const int* mask = (const int*)d_in[15];
  const int* tags = (const int*)d_in[16];

  char* ws = (char*)d_ws;
  size_t off = 0;
  auto take = [&](size_t bytes) -> char* {
    char* p = ws + off;
    off = (off + bytes + 255) & ~(size_t)255;
    return p;
  };
  uint16_t* wb0 = (uint16_t*)take((size_t)2048 * 256 * 2);
  uint16_t* wb1 = (uint16_t*)take((size_t)2048 * 512 * 2);
  uint16_t* xg = (uint16_t*)take((size_t)2 * BS_ * 1024 * 2);
  uint16_t* x1 = (uint16_t*)take((size_t)BS_ * 512 * 2);
  float* feats = (float*)take((size_t)BS_ * TAGS * 4);
  uint64_t* hbuf = (uint64_t*)take((size_t)2 * 8 * 4096 * 8);
  if (off > ws_size) return;
  float* out = (float*)d_out;

  hipLaunchKernelGGL(k_init, dim3(1), dim3(256), 0, stream, out, out_size);
  hipLaunchKernelGGL(k_f2bf, dim3(512), dim3(256), 0, stream, w_ih0, wb0, 2048 * 256);
  hipLaunchKernelGGL(k_f2bf, dim3(512), dim3(256), 0, stream, w_ih1, wb1, 2048 * 512);
  // layer 0
  hipLaunchKernelGGL((k_gemm<true, 256>), dim3(4096), dim3(256), 0, stream, emb, word,
                     (const uint16_t*)nullptr, wb0, xg);
  hipLaunchKernelGGL(k_rec, dim3(64), dim3(256), 0, stream, xg, w_hh0, b_ih0, b_hh0, x1, hbuf,
                     0);
  // layer 1
  hipLaunchKernelGGL((k_gemm<false, 512>), dim3(4096), dim3(256), 0, stream,
                     (const float*)nullptr, (const int*)nullptr, x1, wb1, xg);
  hipLaunchKernelGGL(k_rec, dim3(64), dim3(256), 0, stream, xg, w_hh1, b_ih1, b_hh1, x1, hbuf,
                     256);
  // head
  hipLaunchKernelGGL(k_lnproj, dim3(8192), dim3(256), 0, stream, x1, ln_g, ln_b, w_out, b_out,
                     feats);
  hipLaunchKernelGGL(k_crf, dim3(128), dim3(64), 0, stream, feats, trans, mask, tags, out);
}

// Round 7
// 1797.097 us; speedup vs baseline: 1.0809x; 1.0809x over previous
//
#include <hip/hip_runtime.h>
#include <stdint.h>

#define DEVINL __device__ __forceinline__

typedef __attribute__((ext_vector_type(8))) __bf16 bf16x8;
typedef __attribute__((ext_vector_type(8))) unsigned short ushort8;
typedef __attribute__((ext_vector_type(4))) float floatx4;

constexpr int E_ = 256;
constexpr int TAGS = 22, ST_START = 20, ST_STOP = 21;
constexpr int B_ = 128, S_ = 256, BS_ = B_ * S_;
constexpr int NG = 1024;  // 4*H

DEVINL uint16_t f2bf(float f) {  // RNE f32->bf16 (no NaN inputs expected)
  uint32_t u = __builtin_bit_cast(uint32_t, f);
  return (uint16_t)((u + 0x7fffu + ((u >> 16) & 1u)) >> 16);
}
DEVINL float bf2f(uint16_t h) {
  uint32_t u = ((uint32_t)h) << 16;
  return __builtin_bit_cast(float, u);
}
DEVINL uint4 pack8(float4 a, float4 b) {
  ushort8 h;
  h[0] = f2bf(a.x); h[1] = f2bf(a.y); h[2] = f2bf(a.z); h[3] = f2bf(a.w);
  h[4] = f2bf(b.x); h[5] = f2bf(b.y); h[6] = f2bf(b.z); h[7] = f2bf(b.w);
  return __builtin_bit_cast(uint4, h);
}
DEVINL floatx4 mfma16(uint4 a, uint4 b, floatx4 c) {
  return __builtin_amdgcn_mfma_f32_16x16x32_bf16(
      __builtin_bit_cast(bf16x8, a), __builtin_bit_cast(bf16x8, b), c, 0, 0, 0);
}
DEVINL float sigf(float x) { return 1.f / (1.f + __expf(-x)); }
DEVINL float tanh_(float x) { return 1.f - 2.f / (__expf(2.f * x) + 1.f); }

// ---------------- init: zero output (ws is poisoned 0xAA) ----------
__global__ void k_init(float* out, int out_n) {
  int t = threadIdx.x;
  if (t < out_n) out[t] = 0.f;
}

// ---------------- f32 -> bf16 weight conversion ----------------
__global__ void k_f2bf(const float* __restrict__ src, uint16_t* __restrict__ dst, int n) {
  int i = blockIdx.x * blockDim.x + threadIdx.x;
  int stride = gridDim.x * blockDim.x;
  for (; i < n; i += stride) dst[i] = f2bf(src[i]);
}

// ---------------- xg GEMM: out[m, ng] = A[m,:] . wb[ng,:]  (ng = dir*1024+n) ----
template <bool EMBED, int K>
__global__ __launch_bounds__(256) void k_gemm(
    const float* __restrict__ emb, const int* __restrict__ word,
    const uint16_t* __restrict__ xa, const uint16_t* __restrict__ wb,
    uint16_t* __restrict__ xg) {
  __shared__ uint4 As[8 * 128];  // [k8][m][8] bf16, 16KB
  __shared__ uint4 Bs[8 * 128];  // [k8][n][8] bf16, 16KB
  const int tid = threadIdx.x;
  const int bx = blockIdx.x;
  const int m0 = (bx & 255) << 7;
  const int n0 = (bx >> 8) << 7;
  const int lane = tid & 63, w = tid >> 6;
  const int ln = lane & 15, q = lane >> 4;
  const int wm = w & 1, wn = w >> 1;

  floatx4 acc[4][4];
#pragma unroll
  for (int a = 0; a < 4; a++)
#pragma unroll
    for (int b = 0; b < 4; b++) acc[a][b] = (floatx4){0.f, 0.f, 0.f, 0.f};

  for (int k0 = 0; k0 < K; k0 += 64) {
#pragma unroll
    for (int it = 0; it < 4; it++) {
      int c = tid + it * 256;  // 0..1023
      int k8 = c & 7, r = c >> 3;
      if (EMBED) {
        int row = word[m0 + r];
        const float* sp = emb + (size_t)row * E_ + k0 + k8 * 8;
        float4 f0 = *(const float4*)sp;
        float4 f1 = *(const float4*)(sp + 4);
        As[k8 * 128 + r] = pack8(f0, f1);
      } else {
        As[k8 * 128 + r] = *(const uint4*)(xa + (size_t)(m0 + r) * K + k0 + k8 * 8);
      }
      Bs[k8 * 128 + r] = *(const uint4*)(wb + (size_t)(n0 + r) * K + k0 + k8 * 8);
    }
    __syncthreads();
#pragma unroll
    for (int kk = 0; kk < 2; kk++) {
      const int k4b = kk * 4 + q;
      uint4 af[4], bf[4];
#pragma unroll
      for (int mt = 0; mt < 4; mt++) af[mt] = As[k4b * 128 + wm * 64 + mt * 16 + ln];
#pragma unroll
      for (int nt = 0; nt < 4; nt++) bf[nt] = Bs[k4b * 128 + wn * 64 + nt * 16 + ln];
#pragma unroll
      for (int mt = 0; mt < 4; mt++)
#pragma unroll
        for (int nt = 0; nt < 4; nt++) acc[mt][nt] = mfma16(af[mt], bf[nt], acc[mt][nt]);
    }
    __syncthreads();
  }
#pragma unroll
  for (int mt = 0; mt < 4; mt++) {
    int Rb = m0 + wm * 64 + mt * 16 + q * 4;
#pragma unroll
    for (int nt = 0; nt < 4; nt++) {
      int C = n0 + wn * 64 + nt * 16 + ln;
      size_t base = (size_t)(C >> 10) * ((size_t)BS_ * NG) + (C & 1023);
#pragma unroll
      for (int r = 0; r < 4; r++) xg[base + (size_t)(Rb + r) * NG] = f2bf(acc[mt][nt][r]);
    }
  }
}

// ---------------- BiLSTM recurrence (one layer, both dirs) ----------------
// 128 WGs x 256 thr. group = (dir, batch-tile of 32) -> 8 groups, 16 members each
// owning 16 h-cols. Cross-WG h exchange: epoch-stamped 8B entries {epoch|hpack}.
// NEW: runtime XCD-affinity negotiation (HW_REG_XCC_ID). If all 16 members of a
// group share an XCD (expected under round-robin dispatch), exchange runs at
// WORKGROUP scope (served by the XCD L2, ~200cyc) instead of AGENT scope (LLC).
// Correct either way; every 4th poll round escalates to agent scope as a
// stale-L1 safety valve (agent loads still probe local L2 and see dirty lines).
__global__ __launch_bounds__(256) void k_rec(
    const uint16_t* __restrict__ xg, const float* __restrict__ w_hh,
    const float* __restrict__ b_ih, const float* __restrict__ b_hh,
    uint16_t* __restrict__ xout, uint64_t* __restrict__ hbuf, int ebase) {
  __shared__ uint4 Wl[32 * 64];          // B-frag layout [k4][n=64], 32KB
  __shared__ uint32_t hA32[4096];        // A-frag [k4b(32)][m(32)][c(4)] u32, 16KB
  __shared__ float gates[32 * 66];       // [m][64 gate cols], stride 66 (bank-spread)
  __shared__ uint32_t xstage[16 * 256];  // [slot(16)][jp(8)][msr(32)], 16KB
  __shared__ float bias_s[64];
  __shared__ int negf;

  const int tid = threadIdx.x;
  const int wg = blockIdx.x;
  const int group = wg & 7, member = wg >> 3;    // 8 groups x 16 members
  const int dir = group & 1, tile = group >> 1;  // 4 tiles of 32 rows
  const int j0 = member * 16;
  const int lane = tid & 63, w = tid >> 6, ln = lane & 15, q = lane >> 4;

  // ---- XCD-affinity negotiation: publish own XCC id (agent scope) ----
  uint32_t xcc;
  asm volatile("s_getreg_b32 %0, hwreg(HW_REG_XCC_ID, 0, 32)" : "=s"(xcc));
  xcc &= 7u;
  uint64_t* nego = hbuf + 65536;  // after 2*8*4096 data entries
  const uint32_t wantn = 0x5AFE0000u + (uint32_t)ebase;
  if (tid == 0)
    __hip_atomic_store(&nego[group * 16 + member], (((uint64_t)wantn) << 32) | xcc,
                       __ATOMIC_RELAXED, __HIP_MEMORY_SCOPE_AGENT);

  // stage w_hh slice -> LDS (bf16, B-fragment layout). col n -> gate g=n>>4, j=j0+(n&15)
  for (int p = tid; p < 2048; p += 256) {
    int n = p & 63, k4 = p >> 6;
    int row = dir * 1024 + (n >> 4) * 256 + j0 + (n & 15);
    const float* sp = w_hh + (size_t)row * 256 + k4 * 8;
    float4 f0 = *(const float4*)sp;
    float4 f1 = *(const float4*)(sp + 4);
    Wl[k4 * 64 + n] = pack8(f0, f1);
  }
  if (tid < 64) {
    int row = dir * 1024 + (tid >> 4) * 256 + j0 + (tid & 15);
    bias_s[tid] = b_ih[row] + b_hh[row];
  }
  // ---- resolve negotiation (wave 0) while staging finishes ----
  if (tid < 64) {
    bool ok = true;
    if (tid < 16) {
      uint64_t v;
      do {
        v = __hip_atomic_load(&nego[group * 16 + tid], __ATOMIC_RELAXED,
                              __HIP_MEMORY_SCOPE_AGENT);
      } while ((uint32_t)(v >> 32) != wantn);
      ok = ((uint32_t)v == xcc);
    }
    unsigned long long bal = __ballot(ok);
    if (tid == 0) negf = (bal == 0xFFFFFFFFFFFFFFFFull) ? 1 : 0;
  }
  __syncthreads();
  const bool l2fast = (negf != 0);

  const int nloc = w * 16 + ln;         // gate col 0..63 (gate = w)
  const int nglob = w * 256 + j0 + ln;  // col in [0,1024)
  const float breg = bias_s[nloc];
  const uint16_t* xgd = xg + (size_t)dir * BS_ * NG;

  // state thread: row msr (0..31), col pair cp = member*8 + jp (cols 2cp, 2cp+1)
  const int msr = tid & 31, jp = tid >> 5;
  const int cp = member * 8 + jp;
  const int e_pub = (cp >> 2) * 128 + msr * 4 + (cp & 3);  // A-frag-flattened entry
  float c0 = 0.f, c1 = 0.f;

  // rows this thread's MFMA accs cover (for xg prefetch)
  const int xr0 = tile * 32 + q * 4;  // acc0 rows xr0..xr0+3 ; acc1 rows +16
  int sg = dir ? 255 : 0;
  uint16_t xv[8];
#pragma unroll
  for (int r = 0; r < 4; r++) {
    xv[r] = xgd[(size_t)((xr0 + r) * 256 + sg) * NG + nglob];
    xv[4 + r] = xgd[(size_t)((xr0 + 16 + r) * 256 + sg) * NG + nglob];
  }

  const uint4* hAv = (const uint4*)hA32;

  for (int t = 0; t < 256; t++) {
    sg = dir ? (255 - t) : t;
    floatx4 acc0 = (floatx4){0.f, 0.f, 0.f, 0.f};
    floatx4 acc1 = (floatx4){0.f, 0.f, 0.f, 0.f};
    if (t > 0) {
      // gather h(t-1): batched parallel poll of 16 epoch-stamped entries/thread
      const uint64_t* hsrc = hbuf + (size_t)((((t - 1) & 1) * 8) + group) * 4096;
      const uint32_t want = (uint32_t)(ebase + t);
      uint64_t v[16];
      int rounds = 0;
      while (true) {
        if (l2fast && ((rounds & 3) != 3)) {
#pragma unroll
          for (int i = 0; i < 16; i++)
            v[i] = __hip_atomic_load(&hsrc[tid + 256 * i], __ATOMIC_RELAXED,
                                     __HIP_MEMORY_SCOPE_WORKGROUP);
        } else {
#pragma unroll
          for (int i = 0; i < 16; i++)
            v[i] = __hip_atomic_load(&hsrc[tid + 256 * i], __ATOMIC_RELAXED,
                                     __HIP_MEMORY_SCOPE_AGENT);
        }
        bool fresh = true;
#pragma unroll
        for (int i = 0; i < 16; i++) fresh &= ((uint32_t)(v[i] >> 32) == want);
        if (fresh) break;
        rounds++;
        __builtin_amdgcn_s_sleep(1);
      }
#pragma unroll
      for (int i = 0; i < 16; i++) hA32[tid + 256 * i] = (uint32_t)v[i];
      __syncthreads();
#pragma unroll
      for (int kk = 0; kk < 8; kk++) {
        int k4b = kk * 4 + q;
        uint4 bfr = Wl[k4b * 64 + nloc];
        acc0 = mfma16(hAv[k4b * 32 + ln], bfr, acc0);
        acc1 = mfma16(hAv[k4b * 32 + 16 + ln], bfr, acc1);
      }
    }
    // gate preactivation: W*h + x_t@w_ih (precomputed) + (b_ih+b_hh)
#pragma unroll
    for (int r = 0; r < 4; r++) {
      gates[(q * 4 + r) * 66 + nloc] = acc0[r] + bf2f(xv[r]) + breg;
      gates[(16 + q * 4 + r) * 66 + nloc] = acc1[r] + bf2f(xv[4 + r]) + breg;
    }
    __syncthreads();
    // state update (gate order i,f,g,o): row msr, cols 2cp, 2cp+1
    const float* gr = gates + msr * 66 + 2 * jp;
    float ig0 = gr[0], fg0 = gr[16], gg0 = gr[32], og0 = gr[48];
    float ig1 = gr[1], fg1 = gr[17], gg1 = gr[33], og1 = gr[49];
    c0 = sigf(fg0) * c0 + sigf(ig0) * tanh_(gg0);
    c1 = sigf(fg1) * c1 + sigf(ig1) * tanh_(gg1);
    float h0 = sigf(og0) * tanh_(c0);
    float h1 = sigf(og1) * tanh_(c1);
    uint32_t hpack = (uint32_t)f2bf(h0) | ((uint32_t)f2bf(h1) << 16);
    // publish ASAP (critical path)
    if (t < 255) {
      uint64_t pk = (uint64_t)hpack | ((uint64_t)(uint32_t)(ebase + t + 1) << 32);
      uint64_t* hdst = &hbuf[(size_t)(((t & 1) * 8) + group) * 4096 + e_pub];
      if (l2fast)
        __hip_atomic_store(hdst, pk, __ATOMIC_RELAXED, __HIP_MEMORY_SCOPE_WORKGROUP);
      else
        __hip_atomic_store(hdst, pk, __ATOMIC_RELAXED, __HIP_MEMORY_SCOPE_AGENT);
    }
    xstage[(t & 15) * 256 + jp * 32 + msr] = hpack;
    if ((t & 15) == 15) {
      __syncthreads();  // all xstage writes for slots t-15..t visible
#pragma unroll
      for (int pp = 0; pp < 2; pp++) {
        int p = tid + pp * 256;
        int m = p & 31, u = p >> 5;  // u 0..15
        int tt = t - 15 + u;
        int ssg = dir ? (255 - tt) : tt;
        uint32_t d[8];
#pragma unroll
        for (int jj = 0; jj < 8; jj++) d[jj] = xstage[u * 256 + jj * 32 + m];
        uint16_t* dst = xout + ((size_t)(tile * 32 + m) * 256 + ssg) * 512 + dir * 256 + j0;
        ((uint4*)dst)[0] = (uint4){d[0], d[1], d[2], d[3]};
        ((uint4*)dst)[1] = (uint4){d[4], d[5], d[6], d[7]};
      }
    }
    // xv prefetch for t+1 -- at loop tail so its vmcnt drain is absorbed by the
    // next step's gather wait instead of the pre-state-update barrier
    {
      int tn = (t < 255) ? (t + 1) : 255;
      int sgn = dir ? (255 - tn) : tn;
#pragma unroll
      for (int r = 0; r < 4; r++) {
        xv[r] = xgd[(size_t)((xr0 + r) * 256 + sgn) * NG + nglob];
        xv[4 + r] = xgd[(size_t)((xr0 + 16 + r) * 256 + sgn) * NG + nglob];
      }
    }
  }
}

// ---------------- LayerNorm + projection to 22 tags ----------------
__global__ __launch_bounds__(256) void k_lnproj(
    const uint16_t* __restrict__ x2, const float* __restrict__ ln_g,
    const float* __restrict__ ln_b, const float* __restrict__ w_out,
    const float* __restrict__ b_out, float* __restrict__ feats) {
  const int w = threadIdx.x >> 6, lane = threadIdx.x & 63;
  const int row = blockIdx.x * 4 + w;
  ushort8 xu = __builtin_bit_cast(ushort8, *((const uint4*)(x2 + (size_t)row * 512) + lane));
  float f[8];
  float s = 0.f, ss = 0.f;
#pragma unroll
  for (int j = 0; j < 8; j++) {
    f[j] = bf2f(xu[j]);
    s += f[j];
    ss += f[j] * f[j];
  }
#pragma unroll
  for (int o = 1; o < 64; o <<= 1) {
    s += __shfl_xor(s, o, 64);
    ss += __shfl_xor(ss, o, 64);
  }
  float mu = s * (1.f / 512.f);
  float var = ss * (1.f / 512.f) - mu * mu;
  float rs = rsqrtf(var + 1e-5f);
  const float4 g0 = *(const float4*)(ln_g + lane * 8);
  const float4 g1 = *(const float4*)(ln_g + lane * 8 + 4);
  const float4 bb0 = *(const float4*)(ln_b + lane * 8);
  const float4 bb1 = *(const float4*)(ln_b + lane * 8 + 4);
  float gl[8] = {g0.x, g0.y, g0.z, g0.w, g1.x, g1.y, g1.z, g1.w};
  float bl[8] = {bb0.x, bb0.y, bb0.z, bb0.w, bb1.x, bb1.y, bb1.z, bb1.w};
  float xh[8];
#pragma unroll
  for (int j = 0; j < 8; j++) xh[j] = (f[j] - mu) * rs * gl[j] + bl[j];
  float* fr = feats + (size_t)row * TAGS;
  for (int tg = 0; tg < TAGS; tg++) {
    const float4 w0 = *(const float4*)(w_out + tg * 512 + lane * 8);
    const float4 w1 = *(const float4*)(w_out + tg * 512 + lane * 8 + 4);
    float p = xh[0] * w0.x + xh[1] * w0.y + xh[2] * w0.z + xh[3] * w0.w + xh[4] * w1.x +
              xh[5] * w1.y + xh[6] * w1.z + xh[7] * w1.w;
#pragma unroll
    for (int o = 1; o < 64; o <<= 1) p += __shfl_xor(p, o, 64);
    if (lane == 0) fr[tg] = p + b_out[tg];
  }
}

// ---------------- CRF NLL: one wave per batch row ----------------
__global__ __launch_bounds__(64) void k_crf(
    const float* __restrict__ feats, const float* __restrict__ trans,
    const int* __restrict__ mask, const int* __restrict__ tags, float* __restrict__ out) {
  const int b = blockIdx.x, j = threadIdx.x;
  const bool act = j < TAGS;
  float tcol[TAGS];
#pragma unroll
  for (int i = 0; i < TAGS; i++) tcol[i] = act ? trans[i * TAGS + j] : 0.f;
  const float tstop = act ? trans[j * TAGS + ST_STOP] : 0.f;
  const float* fb = feats + (size_t)b * 256 * TAGS;
  const int* mb = mask + b * 256;
  const int* tb = tags + b * 256;
  float alpha = act ? (tcol[ST_START] + fb[j]) : -1e30f;
  for (int t = 1; t < 256; t++) {
    float vv[TAGS];
    float mx = -1e30f;
#pragma unroll
    for (int i = 0; i < TAGS; i++) {
      float v = __shfl(alpha, i, 64) + tcol[i];
      vv[i] = v;
      mx = fmaxf(mx, v);
    }
    float s = 0.f;
#pragma unroll
    for (int i = 0; i < TAGS; i++) s += __expf(vv[i] - mx);
    float nw = mx + __logf(s) + (act ? fb[t * TAGS + j] : 0.f);
    if (act && mb[t] > 0) alpha = nw;
  }
  float z = act ? (alpha + tstop) : -1e30f;
  float mz = z;
#pragma unroll
  for (int o = 1; o < 64; o <<= 1) mz = fmaxf(mz, __shfl_xor(mz, o, 64));
  float se = act ? __expf(z - mz) : 0.f;
#pragma unroll
  for (int o = 1; o < 64; o <<= 1) se += __shfl_xor(se, o, 64);
  float logZ = mz + __logf(se);
  float em = 0.f;
  int cnt = 0;
  for (int tt = j; tt < 256; tt += 64) {
    int m = mb[tt];
    cnt += m;
    if (m > 0) em += fb[tt * TAGS + tb[tt]];
  }
#pragma unroll
  for (int o = 1; o < 64; o <<= 1) {
    em += __shfl_xor(em, o, 64);
    cnt += __shfl_xor(cnt, o, 64);
  }
  float tr = 0.f;
  for (int tt = 1 + j; tt < 256; tt += 64)
    if (mb[tt] > 0) tr += trans[tb[tt - 1] * TAGS + tb[tt]];
#pragma unroll
  for (int o = 1; o < 64; o <<= 1) tr += __shfl_xor(tr, o, 64);
  if (j == 0) {
    tr += trans[ST_START * TAGS + tb[0]];
    int last = cnt - 1;
    tr += trans[tb[last] * TAGS + ST_STOP];
    atomicAdd(out, (logZ - em - tr) * (1.f / 128.f));
  }
}

extern "C" void kernel_launch(void* const* d_in, const int* in_sizes, int n_in, void* d_out,
                              int out_size, void* d_ws, size_t ws_size, hipStream_t stream) {
  (void)in_sizes;
  (void)n_in;
  const float* emb = (const float*)d_in[0];
  const float* w_ih0 = (const float*)d_in[1];
  const float* w_hh0 = (const float*)d_in[2];
  const float* b_ih0 = (const float*)d_in[3];
  const float* b_hh0 = (const float*)d_in[4];
  const float* w_ih1 = (const float*)d_in[5];
  const float* w_hh1 = (const float*)d_in[6];
  const float* b_ih1 = (const float*)d_in[7];
  const float* b_hh1 = (const float*)d_in[8];
  const float* ln_g = (const float*)d_in[9];
  const float* ln_b = (const float*)d_in[10];
  const float* w_out = (const float*)d_in[11];
  const float* b_out = (const float*)d_in[12];
  const float* trans = (const float*)d_in[13];
  const int* word = (const int*)d_in[14];
  const int* mask = (const int*)d_in[15];
  const int* tags = (const int*)d_in[16];

  char* ws = (char*)d_ws;
  size_t off = 0;
  auto take = [&](size_t bytes) -> char* {
    char* p = ws + off;
    off = (off + bytes + 255) & ~(size_t)255;
    return p;
  };
  uint16_t* wb0 = (uint16_t*)take((size_t)2048 * 256 * 2);
  uint16_t* wb1 = (uint16_t*)take((size_t)2048 * 512 * 2);
  uint16_t* xg = (uint16_t*)take((size_t)2 * BS_ * 1024 * 2);
  uint16_t* x1 = (uint16_t*)take((size_t)BS_ * 512 * 2);
  float* feats = (float*)take((size_t)BS_ * TAGS * 4);
  uint64_t* hbuf = (uint64_t*)take(((size_t)2 * 8 * 4096 + 256) * 8);
  if (off > ws_size) return;
  float* out = (float*)d_out;

  hipLaunchKernelGGL(k_init, dim3(1), dim3(256), 0, stream, out, out_size);
  hipLaunchKernelGGL(k_f2bf, dim3(512), dim3(256), 0, stream, w_ih0, wb0, 2048 * 256);
  hipLaunchKernelGGL(k_f2bf, dim3(512), dim3(256), 0, stream, w_ih1, wb1, 2048 * 512);
  // layer 0
  hipLaunchKernelGGL((k_gemm<true, 256>), dim3(4096), dim3(256), 0, stream, emb, word,
                     (const uint16_t*)nullptr, wb0, xg);
  hipLaunchKernelGGL(k_rec, dim3(128), dim3(256), 0, stream, xg, w_hh0, b_ih0, b_hh0, x1, hbuf,
                     0);
  // layer 1
  hipLaunchKernelGGL((k_gemm<false, 512>), dim3(4096), dim3(256), 0, stream,
                     (const float*)nullptr, (const int*)nullptr, x1, wb1, xg);
  hipLaunchKernelGGL(k_rec, dim3(128), dim3(256), 0, stream, xg, w_hh1, b_ih1, b_hh1, x1, hbuf,
                     256);
  // head
  hipLaunchKernelGGL(k_lnproj, dim3(8192), dim3(256), 0, stream, x1, ln_g, ln_b, w_out, b_out,
                     feats);
  hipLaunchKernelGGL(k_crf, dim3(128), dim3(64), 0, stream, feats, trans, mask, tags, out);
}

// Round 8
// 1650.036 us; speedup vs baseline: 1.1773x; 1.0891x over previous
//
#include <hip/hip_runtime.h>
#include <stdint.h>

#define DEVINL __device__ __forceinline__

typedef __attribute__((ext_vector_type(8))) __bf16 bf16x8;
typedef __attribute__((ext_vector_type(8))) unsigned short ushort8;
typedef __attribute__((ext_vector_type(4))) float floatx4;

constexpr int E_ = 256;
constexpr int TAGS = 22, ST_START = 20, ST_STOP = 21;
constexpr int B_ = 128, S_ = 256, BS_ = B_ * S_;
constexpr int NG = 1024;  // 4*H

DEVINL uint16_t f2bf(float f) {  // RNE f32->bf16 (no NaN inputs expected)
  uint32_t u = __builtin_bit_cast(uint32_t, f);
  return (uint16_t)((u + 0x7fffu + ((u >> 16) & 1u)) >> 16);
}
DEVINL float bf2f(uint16_t h) {
  uint32_t u = ((uint32_t)h) << 16;
  return __builtin_bit_cast(float, u);
}
DEVINL uint4 pack8(float4 a, float4 b) {
  ushort8 h;
  h[0] = f2bf(a.x); h[1] = f2bf(a.y); h[2] = f2bf(a.z); h[3] = f2bf(a.w);
  h[4] = f2bf(b.x); h[5] = f2bf(b.y); h[6] = f2bf(b.z); h[7] = f2bf(b.w);
  return __builtin_bit_cast(uint4, h);
}
DEVINL floatx4 mfma16(uint4 a, uint4 b, floatx4 c) {
  return __builtin_amdgcn_mfma_f32_16x16x32_bf16(
      __builtin_bit_cast(bf16x8, a), __builtin_bit_cast(bf16x8, b), c, 0, 0, 0);
}
DEVINL float sigf(float x) { return 1.f / (1.f + __expf(-x)); }
DEVINL float tanh_(float x) { return 1.f - 2.f / (__expf(2.f * x) + 1.f); }

// ---------------- init: zero output (ws is poisoned 0xAA) ----------
__global__ void k_init(float* out, int out_n) {
  int t = threadIdx.x;
  if (t < out_n) out[t] = 0.f;
}

// ---------------- f32 -> bf16 weight conversion ----------------
__global__ void k_f2bf(const float* __restrict__ src, uint16_t* __restrict__ dst, int n) {
  int i = blockIdx.x * blockDim.x + threadIdx.x;
  int stride = gridDim.x * blockDim.x;
  for (; i < n; i += stride) dst[i] = f2bf(src[i]);
}

// ---------------- xg GEMM: out[m, ng] = A[m,:] . wb[ng,:]  (ng = dir*1024+n) ----
template <bool EMBED, int K>
__global__ __launch_bounds__(256) void k_gemm(
    const float* __restrict__ emb, const int* __restrict__ word,
    const uint16_t* __restrict__ xa, const uint16_t* __restrict__ wb,
    uint16_t* __restrict__ xg) {
  __shared__ uint4 As[8 * 128];  // [k8][m][8] bf16, 16KB
  __shared__ uint4 Bs[8 * 128];  // [k8][n][8] bf16, 16KB
  const int tid = threadIdx.x;
  const int bx = blockIdx.x;
  const int m0 = (bx & 255) << 7;
  const int n0 = (bx >> 8) << 7;
  const int lane = tid & 63, w = tid >> 6;
  const int ln = lane & 15, q = lane >> 4;
  const int wm = w & 1, wn = w >> 1;

  floatx4 acc[4][4];
#pragma unroll
  for (int a = 0; a < 4; a++)
#pragma unroll
    for (int b = 0; b < 4; b++) acc[a][b] = (floatx4){0.f, 0.f, 0.f, 0.f};

  for (int k0 = 0; k0 < K; k0 += 64) {
#pragma unroll
    for (int it = 0; it < 4; it++) {
      int c = tid + it * 256;  // 0..1023
      int k8 = c & 7, r = c >> 3;
      if (EMBED) {
        int row = word[m0 + r];
        const float* sp = emb + (size_t)row * E_ + k0 + k8 * 8;
        float4 f0 = *(const float4*)sp;
        float4 f1 = *(const float4*)(sp + 4);
        As[k8 * 128 + r] = pack8(f0, f1);
      } else {
        As[k8 * 128 + r] = *(const uint4*)(xa + (size_t)(m0 + r) * K + k0 + k8 * 8);
      }
      Bs[k8 * 128 + r] = *(const uint4*)(wb + (size_t)(n0 + r) * K + k0 + k8 * 8);
    }
    __syncthreads();
#pragma unroll
    for (int kk = 0; kk < 2; kk++) {
      const int k4b = kk * 4 + q;
      uint4 af[4], bf[4];
#pragma unroll
      for (int mt = 0; mt < 4; mt++) af[mt] = As[k4b * 128 + wm * 64 + mt * 16 + ln];
#pragma unroll
      for (int nt = 0; nt < 4; nt++) bf[nt] = Bs[k4b * 128 + wn * 64 + nt * 16 + ln];
#pragma unroll
      for (int mt = 0; mt < 4; mt++)
#pragma unroll
        for (int nt = 0; nt < 4; nt++) acc[mt][nt] = mfma16(af[mt], bf[nt], acc[mt][nt]);
    }
    __syncthreads();
  }
#pragma unroll
  for (int mt = 0; mt < 4; mt++) {
    int Rb = m0 + wm * 64 + mt * 16 + q * 4;
#pragma unroll
    for (int nt = 0; nt < 4; nt++) {
      int C = n0 + wn * 64 + nt * 16 + ln;
      size_t base = (size_t)(C >> 10) * ((size_t)BS_ * NG) + (C & 1023);
#pragma unroll
      for (int r = 0; r < 4; r++) xg[base + (size_t)(Rb + r) * NG] = f2bf(acc[mt][nt][r]);
    }
  }
}

// ---------------- BiLSTM recurrence (one layer, both dirs) ----------------
// 128 WGs x 256 thr. group = (dir, batch-tile of 32) -> 8 groups, 16 members each
// owning 16 h-cols. Cross-WG h exchange: epoch-stamped 8B entries {epoch|hpack}.
// XCD-affinity negotiation (R7, proven engaged): publish stores at WORKGROUP
// scope -> stay dirty in the XCD L2 (WRITE_SIZE collapse proved it). Polls are
// ALWAYS agent-scope loads: bypass stale L1, probe the local L2 which owns the
// line (R7's escalation rounds proved agent loads see same-XCD dirty L2 data).
__global__ __launch_bounds__(256) void k_rec(
    const uint16_t* __restrict__ xg, const float* __restrict__ w_hh,
    const float* __restrict__ b_ih, const float* __restrict__ b_hh,
    uint16_t* __restrict__ xout, uint64_t* __restrict__ hbuf, int ebase) {
  __shared__ uint4 Wl[32 * 64];          // B-frag layout [k4][n=64], 32KB
  __shared__ uint32_t hA32[4096];        // A-frag [k4b(32)][m(32)][c(4)] u32, 16KB
  __shared__ float gates[32 * 66];       // [m][64 gate cols], stride 66 (bank-spread)
  __shared__ uint32_t xstage[16 * 256];  // [slot(16)][jp(8)][msr(32)], 16KB
  __shared__ float bias_s[64];
  __shared__ int negf;

  const int tid = threadIdx.x;
  const int wg = blockIdx.x;
  const int group = wg & 7, member = wg >> 3;    // 8 groups x 16 members
  const int dir = group & 1, tile = group >> 1;  // 4 tiles of 32 rows
  const int j0 = member * 16;
  const int lane = tid & 63, w = tid >> 6, ln = lane & 15, q = lane >> 4;

  // ---- XCD-affinity negotiation: publish own XCC id (agent scope) ----
  uint32_t xcc;
  asm volatile("s_getreg_b32 %0, hwreg(HW_REG_XCC_ID, 0, 32)" : "=s"(xcc));
  xcc &= 7u;
  uint64_t* nego = hbuf + 65536;  // after 2*8*4096 data entries
  const uint32_t wantn = 0x5AFE0000u + (uint32_t)ebase;
  if (tid == 0)
    __hip_atomic_store(&nego[group * 16 + member], (((uint64_t)wantn) << 32) | xcc,
                       __ATOMIC_RELAXED, __HIP_MEMORY_SCOPE_AGENT);

  // stage w_hh slice -> LDS (bf16, B-fragment layout). col n -> gate g=n>>4, j=j0+(n&15)
  for (int p = tid; p < 2048; p += 256) {
    int n = p & 63, k4 = p >> 6;
    int row = dir * 1024 + (n >> 4) * 256 + j0 + (n & 15);
    const float* sp = w_hh + (size_t)row * 256 + k4 * 8;
    float4 f0 = *(const float4*)sp;
    float4 f1 = *(const float4*)(sp + 4);
    Wl[k4 * 64 + n] = pack8(f0, f1);
  }
  if (tid < 64) {
    int row = dir * 1024 + (tid >> 4) * 256 + j0 + (tid & 15);
    bias_s[tid] = b_ih[row] + b_hh[row];
  }
  // ---- resolve negotiation (wave 0) while staging finishes ----
  if (tid < 64) {
    bool ok = true;
    if (tid < 16) {
      uint64_t v;
      do {
        v = __hip_atomic_load(&nego[group * 16 + tid], __ATOMIC_RELAXED,
                              __HIP_MEMORY_SCOPE_AGENT);
      } while ((uint32_t)(v >> 32) != wantn);
      ok = ((uint32_t)v == xcc);
    }
    unsigned long long bal = __ballot(ok);
    if (tid == 0) negf = (bal == 0xFFFFFFFFFFFFFFFFull) ? 1 : 0;
  }
  __syncthreads();
  const bool l2fast = (negf != 0);

  const int nloc = w * 16 + ln;         // gate col 0..63 (gate = w)
  const int nglob = w * 256 + j0 + ln;  // col in [0,1024)
  const float breg = bias_s[nloc];
  const uint16_t* xgd = xg + (size_t)dir * BS_ * NG;

  // state thread: row msr (0..31), col pair cp = member*8 + jp (cols 2cp, 2cp+1)
  const int msr = tid & 31, jp = tid >> 5;
  const int cp = member * 8 + jp;
  const int e_pub = (cp >> 2) * 128 + msr * 4 + (cp & 3);  // A-frag-flattened entry
  float c0 = 0.f, c1 = 0.f;

  // rows this thread's MFMA accs cover (for xg prefetch)
  const int xr0 = tile * 32 + q * 4;  // acc0 rows xr0..xr0+3 ; acc1 rows +16
  int sg = dir ? 255 : 0;
  uint16_t xv[8];
#pragma unroll
  for (int r = 0; r < 4; r++) {
    xv[r] = xgd[(size_t)((xr0 + r) * 256 + sg) * NG + nglob];
    xv[4 + r] = xgd[(size_t)((xr0 + 16 + r) * 256 + sg) * NG + nglob];
  }

  const uint4* hAv = (const uint4*)hA32;

  for (int t = 0; t < 256; t++) {
    sg = dir ? (255 - t) : t;
    floatx4 acc0 = (floatx4){0.f, 0.f, 0.f, 0.f};
    floatx4 acc1 = (floatx4){0.f, 0.f, 0.f, 0.f};
    if (t > 0) {
      // gather h(t-1): batched parallel poll, ALWAYS agent-scope loads
      const uint64_t* hsrc = hbuf + (size_t)((((t - 1) & 1) * 8) + group) * 4096;
      const uint32_t want = (uint32_t)(ebase + t);
      uint64_t v[16];
      while (true) {
#pragma unroll
        for (int i = 0; i < 16; i++)
          v[i] = __hip_atomic_load(&hsrc[tid + 256 * i], __ATOMIC_RELAXED,
                                   __HIP_MEMORY_SCOPE_AGENT);
        bool fresh = true;
#pragma unroll
        for (int i = 0; i < 16; i++) fresh &= ((uint32_t)(v[i] >> 32) == want);
        if (fresh) break;
        __builtin_amdgcn_s_sleep(1);
      }
#pragma unroll
      for (int i = 0; i < 16; i++) hA32[tid + 256 * i] = (uint32_t)v[i];
      __syncthreads();
#pragma unroll
      for (int kk = 0; kk < 8; kk++) {
        int k4b = kk * 4 + q;
        uint4 bfr = Wl[k4b * 64 + nloc];
        acc0 = mfma16(hAv[k4b * 32 + ln], bfr, acc0);
        acc1 = mfma16(hAv[k4b * 32 + 16 + ln], bfr, acc1);
      }
    }
    // gate preactivation: W*h + x_t@w_ih (precomputed) + (b_ih+b_hh)
#pragma unroll
    for (int r = 0; r < 4; r++) {
      gates[(q * 4 + r) * 66 + nloc] = acc0[r] + bf2f(xv[r]) + breg;
      gates[(16 + q * 4 + r) * 66 + nloc] = acc1[r] + bf2f(xv[4 + r]) + breg;
    }
    __syncthreads();
    // state update (gate order i,f,g,o): row msr, cols 2cp, 2cp+1
    const float* gr = gates + msr * 66 + 2 * jp;
    float ig0 = gr[0], fg0 = gr[16], gg0 = gr[32], og0 = gr[48];
    float ig1 = gr[1], fg1 = gr[17], gg1 = gr[33], og1 = gr[49];
    c0 = sigf(fg0) * c0 + sigf(ig0) * tanh_(gg0);
    c1 = sigf(fg1) * c1 + sigf(ig1) * tanh_(gg1);
    float h0 = sigf(og0) * tanh_(c0);
    float h1 = sigf(og1) * tanh_(c1);
    uint32_t hpack = (uint32_t)f2bf(h0) | ((uint32_t)f2bf(h1) << 16);
    // publish ASAP (critical path): stays dirty in XCD L2 on the fast path
    if (t < 255) {
      uint64_t pk = (uint64_t)hpack | ((uint64_t)(uint32_t)(ebase + t + 1) << 32);
      uint64_t* hdst = &hbuf[(size_t)(((t & 1) * 8) + group) * 4096 + e_pub];
      if (l2fast)
        __hip_atomic_store(hdst, pk, __ATOMIC_RELAXED, __HIP_MEMORY_SCOPE_WORKGROUP);
      else
        __hip_atomic_store(hdst, pk, __ATOMIC_RELAXED, __HIP_MEMORY_SCOPE_AGENT);
    }
    xstage[(t & 15) * 256 + jp * 32 + msr] = hpack;
    if ((t & 15) == 15) {
      __syncthreads();  // all xstage writes for slots t-15..t visible
#pragma unroll
      for (int pp = 0; pp < 2; pp++) {
        int p = tid + pp * 256;
        int m = p & 31, u = p >> 5;  // u 0..15
        int tt = t - 15 + u;
        int ssg = dir ? (255 - tt) : tt;
        uint32_t d[8];
#pragma unroll
        for (int jj = 0; jj < 8; jj++) d[jj] = xstage[u * 256 + jj * 32 + m];
        uint16_t* dst = xout + ((size_t)(tile * 32 + m) * 256 + ssg) * 512 + dir * 256 + j0;
        ((uint4*)dst)[0] = (uint4){d[0], d[1], d[2], d[3]};
        ((uint4*)dst)[1] = (uint4){d[4], d[5], d[6], d[7]};
      }
    }
    // xv prefetch for t+1 -- at loop tail so its vmcnt drain is absorbed by the
    // next step's gather wait instead of the pre-state-update barrier
    {
      int tn = (t < 255) ? (t + 1) : 255;
      int sgn = dir ? (255 - tn) : tn;
#pragma unroll
      for (int r = 0; r < 4; r++) {
        xv[r] = xgd[(size_t)((xr0 + r) * 256 + sgn) * NG + nglob];
        xv[4 + r] = xgd[(size_t)((xr0 + 16 + r) * 256 + sgn) * NG + nglob];
      }
    }
  }
}

// ---------------- LayerNorm + projection to 22 tags ----------------
__global__ __launch_bounds__(256) void k_lnproj(
    const uint16_t* __restrict__ x2, const float* __restrict__ ln_g,
    const float* __restrict__ ln_b, const float* __restrict__ w_out,
    const float* __restrict__ b_out, float* __restrict__ feats) {
  const int w = threadIdx.x >> 6, lane = threadIdx.x & 63;
  const int row = blockIdx.x * 4 + w;
  ushort8 xu = __builtin_bit_cast(ushort8, *((const uint4*)(x2 + (size_t)row * 512) + lane));
  float f[8];
  float s = 0.f, ss = 0.f;
#pragma unroll
  for (int j = 0; j < 8; j++) {
    f[j] = bf2f(xu[j]);
    s += f[j];
    ss += f[j] * f[j];
  }
#pragma unroll
  for (int o = 1; o < 64; o <<= 1) {
    s += __shfl_xor(s, o, 64);
    ss += __shfl_xor(ss, o, 64);
  }
  float mu = s * (1.f / 512.f);
  float var = ss * (1.f / 512.f) - mu * mu;
  float rs = rsqrtf(var + 1e-5f);
  const float4 g0 = *(const float4*)(ln_g + lane * 8);
  const float4 g1 = *(const float4*)(ln_g + lane * 8 + 4);
  const float4 bb0 = *(const float4*)(ln_b + lane * 8);
  const float4 bb1 = *(const float4*)(ln_b + lane * 8 + 4);
  float gl[8] = {g0.x, g0.y, g0.z, g0.w, g1.x, g1.y, g1.z, g1.w};
  float bl[8] = {bb0.x, bb0.y, bb0.z, bb0.w, bb1.x, bb1.y, bb1.z, bb1.w};
  float xh[8];
#pragma unroll
  for (int j = 0; j < 8; j++) xh[j] = (f[j] - mu) * rs * gl[j] + bl[j];
  float* fr = feats + (size_t)row * TAGS;
  for (int tg = 0; tg < TAGS; tg++) {
    const float4 w0 = *(const float4*)(w_out + tg * 512 + lane * 8);
    const float4 w1 = *(const float4*)(w_out + tg * 512 + lane * 8 + 4);
    float p = xh[0] * w0.x + xh[1] * w0.y + xh[2] * w0.z + xh[3] * w0.w + xh[4] * w1.x +
              xh[5] * w1.y + xh[6] * w1.z + xh[7] * w1.w;
#pragma unroll
    for (int o = 1; o < 64; o <<= 1) p += __shfl_xor(p, o, 64);
    if (lane == 0) fr[tg] = p + b_out[tg];
  }
}

// ---------------- CRF NLL: one wave per batch row ----------------
__global__ __launch_bounds__(64) void k_crf(
    const float* __restrict__ feats, const float* __restrict__ trans,
    const int* __restrict__ mask, const int* __restrict__ tags, float* __restrict__ out) {
  const int b = blockIdx.x, j = threadIdx.x;
  const bool act = j < TAGS;
  float tcol[TAGS];
#pragma unroll
  for (int i = 0; i < TAGS; i++) tcol[i] = act ? trans[i * TAGS + j] : 0.f;
  const float tstop = act ? trans[j * TAGS + ST_STOP] : 0.f;
  const float* fb = feats + (size_t)b * 256 * TAGS;
  const int* mb = mask + b * 256;
  const int* tb = tags + b * 256;
  float alpha = act ? (tcol[ST_START] + fb[j]) : -1e30f;
  for (int t = 1; t < 256; t++) {
    float vv[TAGS];
    float mx = -1e30f;
#pragma unroll
    for (int i = 0; i < TAGS; i++) {
      float v = __shfl(alpha, i, 64) + tcol[i];
      vv[i] = v;
      mx = fmaxf(mx, v);
    }
    float s = 0.f;
#pragma unroll
    for (int i = 0; i < TAGS; i++) s += __expf(vv[i] - mx);
    float nw = mx + __logf(s) + (act ? fb[t * TAGS + j] : 0.f);
    if (act && mb[t] > 0) alpha = nw;
  }
  float z = act ? (alpha + tstop) : -1e30f;
  float mz = z;
#pragma unroll
  for (int o = 1; o < 64; o <<= 1) mz = fmaxf(mz, __shfl_xor(mz, o, 64));
  float se = act ? __expf(z - mz) : 0.f;
#pragma unroll
  for (int o = 1; o < 64; o <<= 1) se += __shfl_xor(se, o, 64);
  float logZ = mz + __logf(se);
  float em = 0.f;
  int cnt = 0;
  for (int tt = j; tt < 256; tt += 64) {
    int m = mb[tt];
    cnt += m;
    if (m > 0) em += fb[tt * TAGS + tb[tt]];
  }
#pragma unroll
  for (int o = 1; o < 64; o <<= 1) {
    em += __shfl_xor(em, o, 64);
    cnt += __shfl_xor(cnt, o, 64);
  }
  float tr = 0.f;
  for (int tt = 1 + j; tt < 256; tt += 64)
    if (mb[tt] > 0) tr += trans[tb[tt - 1] * TAGS + tb[tt]];
#pragma unroll
  for (int o = 1; o < 64; o <<= 1) tr += __shfl_xor(tr, o, 64);
  if (j == 0) {
    tr += trans[ST_START * TAGS + tb[0]];
    int last = cnt - 1;
    tr += trans[tb[last] * TAGS + ST_STOP];
    atomicAdd(out, (logZ - em - tr) * (1.f / 128.f));
  }
}

extern "C" void kernel_launch(void* const* d_in, const int* in_sizes, int n_in, void* d_out,
                              int out_size, void* d_ws, size_t ws_size, hipStream_t stream) {
  (void)in_sizes;
  (void)n_in;
  const float* emb = (const float*)d_in[0];
  const float* w_ih0 = (const float*)d_in[1];
  const float* w_hh0 = (const float*)d_in[2];
  const float* b_ih0 = (const float*)d_in[3];
  const float* b_hh0 = (const float*)d_in[4];
  const float* w_ih1 = (const float*)d_in[5];
  const float* w_hh1 = (const float*)d_in[6];
  const float* b_ih1 = (const float*)d_in[7];
  const float* b_hh1 = (const float*)d_in[8];
  const float* ln_g = (const float*)d_in[9];
  const float* ln_b = (const float*)d_in[10];
  const float* w_out = (const float*)d_in[11];
  const float* b_out = (const float*)d_in[12];
  const float* trans = (const float*)d_in[13];
  const int* word = (const int*)d_in[14];
  const int* mask = (const int*)d_in[15];
  const int* tags = (const int*)d_in[16];

  char* ws = (char*)d_ws;
  size_t off = 0;
  auto take = [&](size_t bytes) -> char* {
    char* p = ws + off;
    off = (off + bytes + 255) & ~(size_t)255;
    return p;
  };
  uint16_t* wb0 = (uint16_t*)take((size_t)2048 * 256 * 2);
  uint16_t* wb1 = (uint16_t*)take((size_t)2048 * 512 * 2);
  uint16_t* xg = (uint16_t*)take((size_t)2 * BS_ * 1024 * 2);
  uint16_t* x1 = (uint16_t*)take((size_t)BS_ * 512 * 2);
  float* feats = (float*)take((size_t)BS_ * TAGS * 4);
  uint64_t* hbuf = (uint64_t*)take(((size_t)2 * 8 * 4096 + 256) * 8);
  if (off > ws_size) return;
  float* out = (float*)d_out;

  hipLaunchKernelGGL(k_init, dim3(1), dim3(256), 0, stream, out, out_size);
  hipLaunchKernelGGL(k_f2bf, dim3(512), dim3(256), 0, stream, w_ih0, wb0, 2048 * 256);
  hipLaunchKernelGGL(k_f2bf, dim3(512), dim3(256), 0, stream, w_ih1, wb1, 2048 * 512);
  // layer 0
  hipLaunchKernelGGL((k_gemm<true, 256>), dim3(4096), dim3(256), 0, stream, emb, word,
                     (const uint16_t*)nullptr, wb0, xg);
  hipLaunchKernelGGL(k_rec, dim3(128), dim3(256), 0, stream, xg, w_hh0, b_ih0, b_hh0, x1, hbuf,
                     0);
  // layer 1
  hipLaunchKernelGGL((k_gemm<false, 512>), dim3(4096), dim3(256), 0, stream,
                     (const float*)nullptr, (const int*)nullptr, x1, wb1, xg);
  hipLaunchKernelGGL(k_rec, dim3(128), dim3(256), 0, stream, xg, w_hh1, b_ih1, b_hh1, x1, hbuf,
                     256);
  // head
  hipLaunchKernelGGL(k_lnproj, dim3(8192), dim3(256), 0, stream, x1, ln_g, ln_b, w_out, b_out,
                     feats);
  hipLaunchKernelGGL(k_crf, dim3(128), dim3(64), 0, stream, feats, trans, mask, tags, out);
}